// Round 11
// baseline (298.494 us; speedup 1.0000x reference)
//
#include <hip/hip_runtime.h>
#include <hip/hip_bf16.h>
#include <cstdint>
#include <cstddef>

// ---------------------------------------------------------------------------
// Transformer_78941498901000 — round 10: whole-network persistent kernel.
// Dedup (r7): rows depend only on (token, position) => U = 13*128 = 1664.
// Key insight: after dedup EVERY op is row-local (attention mixes only the
// head axis) => zero cross-row deps => one kernel runs all 6 layers + logits
// with blocks owning 16 rows end-to-end, residual resident in LDS.
// 3 dispatches: prep -> net -> scatter_loss.
// d_out = logits f32 [851968] ++ loss f32 [1]
//
// ws layout (bytes), ~14.5 MB:
//   wqkvT @ 0          : bf16 [L][1536][512]  9,437,184  (n-major, k-minor)
//   woT   @ 9,437,184  : bf16 [L][512][512]   3,145,728
//   x0    @ 12,582,912 : bf16 [1664,512]      1,703,936
//   lu    @ 14,286,848 : f32  [1664,13]          86,528
// ---------------------------------------------------------------------------

typedef __attribute__((ext_vector_type(8))) short short8;
typedef __attribute__((ext_vector_type(4))) float f32x4;

__device__ __forceinline__ float bf2f(ushort u) {
    return __uint_as_float(((unsigned int)u) << 16);
}
__device__ __forceinline__ ushort f2bf(float f) {
    unsigned int x = __float_as_uint(f);
    unsigned int r = (x + 0x7fffu + ((x >> 16) & 1u)) >> 16;  // RNE
    return (ushort)r;
}
__device__ __forceinline__ void gload_lds16(const void* g, void* l) {
    __builtin_amdgcn_global_load_lds(
        (const __attribute__((address_space(1))) void*)g,
        (__attribute__((address_space(3))) void*)l, 16, 0, 0);
}

// ---------------- prep: weight transpose (f32 k-major -> bf16 n-major) + x0
__global__ __launch_bounds__(256) void prep_all(
    const float* __restrict__ Wq, const float* __restrict__ Wk,
    const float* __restrict__ Wv, const float* __restrict__ Wo,
    const float* __restrict__ wte, const float* __restrict__ wpe,
    ushort* __restrict__ wqkvT, ushort* __restrict__ woT,
    ushort* __restrict__ x0) {
    __shared__ float lds[64][65];
    const int bid = blockIdx.x;
    const int tid = threadIdx.x;
    if (bid < 1536) {                      // 24 matrices x 64 tiles of 64x64
        const int mat = bid >> 6;
        const int tile = bid & 63;
        const int tr = tile >> 3, tc = tile & 7;
        const int l = mat >> 2, which = mat & 3;
        const float* S;
        switch (which) {
            case 0: S = Wq; break;
            case 1: S = Wk; break;
            case 2: S = Wv; break;
            default: S = Wo; break;
        }
        S += (size_t)l * 262144;
        ushort* T = (which < 3) ? wqkvT + (size_t)l * 786432 + which * 262144
                                : woT + (size_t)l * 262144;
        const int c = tid & 63;
        #pragma unroll
        for (int it = 0; it < 16; it++) {
            int r = it * 4 + (tid >> 6);
            lds[r][c] = S[(size_t)(tr * 64 + r) * 512 + tc * 64 + c];
        }
        __syncthreads();
        #pragma unroll
        for (int it = 0; it < 16; it++) {
            int r = it * 4 + (tid >> 6);
            T[(size_t)(tc * 64 + r) * 512 + tr * 64 + c] = f2bf(lds[c][r]);
        }
    } else {                               // x0 = wte[v] + wpe[t]
        size_t idx = (size_t)(bid - 1536) * 256 + tid;
        size_t u = idx >> 6;               // < 1664
        int c8 = (int)(idx & 63);
        int v = (int)(u >> 7);
        int t = (int)(u & 127);
        const float* ep = wte + (size_t)v * 512 + c8 * 8;
        const float* pp = wpe + (size_t)t * 512 + c8 * 8;
        float4 e0 = *(const float4*)ep, e1 = *(const float4*)(ep + 4);
        float4 p0 = *(const float4*)pp, p1 = *(const float4*)(pp + 4);
        float s[8] = {e0.x + p0.x, e0.y + p0.y, e0.z + p0.z, e0.w + p0.w,
                      e1.x + p1.x, e1.y + p1.y, e1.z + p1.z, e1.w + p1.w};
        short8 o;
        #pragma unroll
        for (int j = 0; j < 8; j++) o[j] = (short)f2bf(s[j]);
        *(short8*)(x0 + u * 512 + c8 * 8) = o;
    }
}

// ---------------- whole network: 6 layers + logits, row-local --------------
// 104 blocks x 512 threads; block owns rows [bid*16, bid*16+16).
// LDS: xcur[16][512] bf16 swizzled (residual / GEMM-A), qkvs[16][1536] bf16
// (qkv out; q-region reused as swizzled hid; [512..1024) reused as pre-LN
// out), Bsh dbuf 2x[256][64] for weight streaming via global_load_lds.
#define RPB 16
__global__ __launch_bounds__(512, 1) void net_kernel(
    const ushort* __restrict__ x0, const ushort* __restrict__ wqkvT,
    const ushort* __restrict__ woT, const float* __restrict__ bq,
    const float* __restrict__ bk, const float* __restrict__ bv,
    const float* __restrict__ bo, const float* __restrict__ ln_g,
    const float* __restrict__ ln_b, const float* __restrict__ Wlm,
    const float* __restrict__ blm, float* __restrict__ lu) {
    __shared__ alignas(16) ushort xcur[RPB * 512];     // 16 KB
    __shared__ alignas(16) ushort qkvs[RPB * 1536];    // 48 KB
    __shared__ alignas(16) ushort Bsh[2][256 * 64];    // 64 KB
    __shared__ float pps[8][RPB], ppss[8][RPB];
    __shared__ float smu[RPB], srs[RPB];
    const int tid = threadIdx.x;
    const int lane = tid & 63;
    const int wave = tid >> 6;            // 0..7
    const int g0row = blockIdx.x * RPB;
    const int r = lane & 15;
    const int kq = (lane >> 4) * 8;
    const int cc = lane & 15;
    const int r4 = (lane >> 4) * 4;

    // stage one 256-row x 64-K weight k-tile into Bsh[b]
    auto stageB = [&](const ushort* Bl, int t, int b) {
        #pragma unroll
        for (int i = 0; i < 4; i++) {
            int ch = (i * 8 + wave) * 64 + lane;       // < 2048
            int row = ch >> 3;
            int c8 = (ch & 7) ^ (row & 7);             // inverse swizzle
            gload_lds16(Bl + (size_t)row * 512 + t * 64 + c8 * 8,
                        (char*)Bsh[b] + ch * 16);
        }
    };

    // ---- load x0 -> xcur (swizzled) ----
    #pragma unroll
    for (int i = 0; i < 2; i++) {
        int ch = tid + i * 512;            // 1024 chunks of 16B
        int rr = ch >> 6, c8 = ch & 63;
        short8 v = *(const short8*)(x0 + (size_t)(g0row + rr) * 512 + c8 * 8);
        int off = (rr * 1024 + c8 * 16) ^ ((rr & 7) << 4);
        *(short8*)((char*)xcur + off) = v;
    }
    __syncthreads();

    for (int l = 0; l < 6; l++) {
        const ushort* Wq_l = wqkvT + (size_t)l * 786432;
        const ushort* Wo_l = woT + (size_t)l * 262144;

        // ---- qkv: qkvs[16][1536] = xcur @ Wq_l^T + bias ----
        for (int nc = 0; nc < 6; nc++) {
            const ushort* Bl = Wq_l + (size_t)(nc * 256) * 512;
            f32x4 acc[2] = {};
            stageB(Bl, 0, 0);
            __syncthreads();
            #pragma unroll
            for (int t = 0; t < 8; t++) {
                const int cur = t & 1;
                if (t < 7) stageB(Bl, t + 1, cur ^ 1);
                #pragma unroll
                for (int kk = 0; kk < 64; kk += 32) {
                    int kA = t * 64 + kk + kq;
                    int aoff = (r * 1024 + kA * 2) ^ ((r & 7) << 4);
                    short8 af = *(const short8*)((const char*)xcur + aoff);
                    #pragma unroll
                    for (int nn = 0; nn < 2; nn++) {
                        int brow = wave * 32 + nn * 16 + r;
                        int boff = (brow * 128 + (kk + kq) * 2) ^ ((brow & 7) << 4);
                        short8 bf8 = *(const short8*)((const char*)Bsh[cur] + boff);
                        acc[nn] = __builtin_amdgcn_mfma_f32_16x16x32_bf16(
                            af, bf8, acc[nn], 0, 0, 0);
                    }
                }
                __syncthreads();
            }
            #pragma unroll
            for (int nn = 0; nn < 2; nn++) {
                int col = nc * 256 + wave * 32 + nn * 16 + cc;
                float bias = (col < 512) ? bq[l * 512 + col]
                           : (col < 1024) ? bk[l * 512 + col - 512]
                                          : bv[l * 512 + col - 1024];
                #pragma unroll
                for (int i = 0; i < 4; i++)
                    qkvs[(r4 + i) * 1536 + col] = f2bf(acc[nn][i] + bias);
            }
        }
        __syncthreads();                    // qkvs complete

        // ---- attention (row-local): hid -> q-region of qkvs, swizzled ----
        {
            const int h = lane >> 3, g = lane & 7;
            #pragma unroll
            for (int it = 0; it < 2; it++) {
                int lrow = wave * 2 + it;
                const ushort* base = qkvs + lrow * 1536;
                const ushort* qp = base + h * 64;
                const ushort* kp = base + 512 + g * 64;
                float s = 0.f;
                #pragma unroll
                for (int dc = 0; dc < 8; dc++) {
                    short8 q8 = *(const short8*)(qp + dc * 8);
                    short8 k8 = *(const short8*)(kp + dc * 8);
                    #pragma unroll
                    for (int j = 0; j < 8; j++)
                        s += bf2f((ushort)q8[j]) * bf2f((ushort)k8[j]);
                }
                s *= 0.125f;
                float mx = s;
                #pragma unroll
                for (int o = 1; o < 8; o <<= 1) mx = fmaxf(mx, __shfl_xor(mx, o));
                float e = __expf(s - mx);
                float den = e;
                #pragma unroll
                for (int o = 1; o < 8; o <<= 1) den += __shfl_xor(den, o);
                float att = e / den;
                float o8[8];
                #pragma unroll
                for (int j = 0; j < 8; j++) o8[j] = 0.f;
                const ushort* vp = base + 1024 + (lane & 7) * 8;
                #pragma unroll
                for (int gg = 0; gg < 8; gg++) {
                    float a = __shfl(att, (lane & 56) | gg);
                    short8 v8 = *(const short8*)(vp + gg * 64);
                    #pragma unroll
                    for (int j = 0; j < 8; j++) o8[j] += a * bf2f((ushort)v8[j]);
                }
                short8 ov;
                #pragma unroll
                for (int j = 0; j < 8; j++) ov[j] = (short)f2bf(o8[j]);
                int off = lrow * 3072 + ((lane * 16) ^ ((lrow & 7) << 4));
                *(short8*)((char*)qkvs + off) = ov;     // hid, swizzled
            }
        }
        __syncthreads();

        // ---- proj: out = hid @ Wo_l^T + bo + xcur; partial stats ----
        float s_i[4] = {0.f, 0.f, 0.f, 0.f}, ss_i[4] = {0.f, 0.f, 0.f, 0.f};
        for (int nc = 0; nc < 2; nc++) {
            const ushort* Bl = Wo_l + (size_t)(nc * 256) * 512;
            f32x4 pacc[2] = {};
            stageB(Bl, 0, 0);
            __syncthreads();
            #pragma unroll
            for (int t = 0; t < 8; t++) {
                const int cur = t & 1;
                if (t < 7) stageB(Bl, t + 1, cur ^ 1);
                #pragma unroll
                for (int kk = 0; kk < 64; kk += 32) {
                    int kA = t * 64 + kk + kq;
                    int aoff = r * 3072 + ((kA * 2) ^ ((r & 7) << 4));
                    short8 af = *(const short8*)((const char*)qkvs + aoff);
                    #pragma unroll
                    for (int nn = 0; nn < 2; nn++) {
                        int brow = wave * 32 + nn * 16 + r;
                        int boff = (brow * 128 + (kk + kq) * 2) ^ ((brow & 7) << 4);
                        short8 bf8 = *(const short8*)((const char*)Bsh[cur] + boff);
                        pacc[nn] = __builtin_amdgcn_mfma_f32_16x16x32_bf16(
                            af, bf8, pacc[nn], 0, 0, 0);
                    }
                }
                __syncthreads();
            }
            #pragma unroll
            for (int nn = 0; nn < 2; nn++) {
                int col = nc * 256 + wave * 32 + nn * 16 + cc;
                float boc = bo[l * 512 + col];
                #pragma unroll
                for (int i = 0; i < 4; i++) {
                    int row = r4 + i;
                    int xoff = (row * 1024 + col * 2) ^ ((row & 7) << 4);
                    float resid = bf2f(*(const ushort*)((const char*)xcur + xoff));
                    float v = pacc[nn][i] + boc + resid;
                    qkvs[row * 1536 + 512 + col] = f2bf(v);   // pre-LN out
                    s_i[i] += v; ss_i[i] += v * v;
                }
            }
        }
        #pragma unroll
        for (int i = 0; i < 4; i++) {
            #pragma unroll
            for (int o = 1; o < 16; o <<= 1) {
                s_i[i] += __shfl_xor(s_i[i], o);
                ss_i[i] += __shfl_xor(ss_i[i], o);
            }
        }
        if (cc == 0) {
            #pragma unroll
            for (int i = 0; i < 4; i++) {
                pps[wave][r4 + i] = s_i[i];
                ppss[wave][r4 + i] = ss_i[i];
            }
        }
        __syncthreads();
        if (tid < RPB) {
            float S = 0.f, SS = 0.f;
            #pragma unroll
            for (int w = 0; w < 8; w++) { S += pps[w][tid]; SS += ppss[w][tid]; }
            float mu = S * (1.f / 512.f);
            float var = SS * (1.f / 512.f) - mu * mu;
            smu[tid] = mu;
            srs[tid] = rsqrtf(var + 1e-5f);
        }
        __syncthreads();
        {   // normalize -> xcur (swizzled). 32 threads/row x 16 cols.
            int row = tid >> 5;
            int c0 = (tid & 31) * 16;
            float mu = smu[row], rs = srs[row];
            const ushort* ob = qkvs + row * 1536 + 512 + c0;
            short8 t0 = *(const short8*)ob;
            short8 t1 = *(const short8*)(ob + 8);
            const float* gp = ln_g + l * 512 + c0;
            const float* bp = ln_b + l * 512 + c0;
            float ga[16], ba[16];
            #pragma unroll
            for (int q = 0; q < 4; q++) {
                float4 gq = *(const float4*)(gp + q * 4);
                float4 bq4 = *(const float4*)(bp + q * 4);
                ga[q * 4 + 0] = gq.x; ga[q * 4 + 1] = gq.y;
                ga[q * 4 + 2] = gq.z; ga[q * 4 + 3] = gq.w;
                ba[q * 4 + 0] = bq4.x; ba[q * 4 + 1] = bq4.y;
                ba[q * 4 + 2] = bq4.z; ba[q * 4 + 3] = bq4.w;
            }
            short8 o0, o1;
            #pragma unroll
            for (int j = 0; j < 8; j++) {
                o0[j] = (short)f2bf((bf2f((ushort)t0[j]) - mu) * rs * ga[j] + ba[j]);
                o1[j] = (short)f2bf((bf2f((ushort)t1[j]) - mu) * rs * ga[8 + j] + ba[8 + j]);
            }
            int off0 = (row * 1024 + c0 * 2) ^ ((row & 7) << 4);
            int off1 = (row * 1024 + c0 * 2 + 16) ^ ((row & 7) << 4);
            *(short8*)((char*)xcur + off0) = o0;
            *(short8*)((char*)xcur + off1) = o1;
        }
        __syncthreads();
    }

    // ---- logits for own 16 rows ----
    float* wl = (float*)Bsh;               // reuse: [j][lane][13] interleave
    if (tid < 512) {
        int k = tid;
        int dst = ((k & 7) * 64 + (k >> 3)) * 13;
        #pragma unroll
        for (int v = 0; v < 13; v++) wl[dst + v] = Wlm[k * 13 + v];
    }
    __syncthreads();
    float bl[13];
    #pragma unroll
    for (int v = 0; v < 13; v++) bl[v] = blm[v];
    #pragma unroll
    for (int it = 0; it < 2; it++) {
        int lrow = wave * 2 + it;
        int off = (lrow * 1024 + lane * 16) ^ ((lrow & 7) << 4);
        short8 xv = *(const short8*)((const char*)xcur + off);
        float p[13];
        #pragma unroll
        for (int v = 0; v < 13; v++) p[v] = 0.f;
        #pragma unroll
        for (int j = 0; j < 8; j++) {
            float xf = bf2f((ushort)xv[j]);
            const float* wr = wl + (j * 64 + lane) * 13;
            #pragma unroll
            for (int v = 0; v < 13; v++) p[v] += xf * wr[v];
        }
        #pragma unroll
        for (int v = 0; v < 13; v++) {
            #pragma unroll
            for (int o = 32; o > 0; o >>= 1) p[v] += __shfl_xor(p[v], o);
        }
        if (lane == 0) {
            #pragma unroll
            for (int v = 0; v < 13; v++)
                lu[(size_t)(g0row + lrow) * 13 + v] = p[v] + bl[v];
        }
    }
}

// ---------------- scatter + loss -------------------------------------------
__global__ __launch_bounds__(256) void scatter_loss(
    const float* __restrict__ lu, const int* __restrict__ tok,
    const int* __restrict__ label, float* __restrict__ out) {
    __shared__ float red[4];
    const int tid = threadIdx.x;
    if (blockIdx.x < 3328) {
        unsigned int i = blockIdx.x * 256 + tid;      // < 851968 exactly
        unsigned int bt = i / 13u;
        unsigned int vv = i - bt * 13u;
        int v = tok[bt];
        int t = (int)(bt & 127u);
        out[i] = lu[(size_t)((v << 7) + t) * 13 + vv];
    } else {
        float acc = 0.f;
        for (int b = tid; b < 512; b += 256) {
            int v = tok[b * 128 + 127];
            const float* lg = lu + (size_t)((v << 7) + 127) * 13;
            float mx = lg[0];
            #pragma unroll
            for (int vv = 1; vv < 13; vv++) mx = fmaxf(mx, lg[vv]);
            float den = 0.f;
            #pragma unroll
            for (int vv = 0; vv < 13; vv++) den += expf(lg[vv] - mx);
            int lab = label[b];
            acc += -(lg[lab] - mx - logf(den));
        }
        #pragma unroll
        for (int o = 32; o > 0; o >>= 1) acc += __shfl_xor(acc, o);
        if ((tid & 63) == 0) red[tid >> 6] = acc;
        __syncthreads();
        if (tid == 0)
            out[851968] = (red[0] + red[1] + red[2] + red[3]) * (1.f / 512.f);
    }
}

// ---------------------------------------------------------------------------
extern "C" void kernel_launch(void* const* d_in, const int* in_sizes, int n_in,
                              void* d_out, int out_size, void* d_ws, size_t ws_size,
                              hipStream_t stream) {
    const int*   tok   = (const int*)d_in[0];
    const int*   label = (const int*)d_in[1];
    const float* wte   = (const float*)d_in[2];
    const float* wpe   = (const float*)d_in[3];
    const float* Wq    = (const float*)d_in[4];
    const float* bq    = (const float*)d_in[5];
    const float* Wk    = (const float*)d_in[6];
    const float* bk    = (const float*)d_in[7];
    const float* Wv    = (const float*)d_in[8];
    const float* bv    = (const float*)d_in[9];
    const float* Wo    = (const float*)d_in[10];
    const float* bo    = (const float*)d_in[11];
    const float* ln_g  = (const float*)d_in[12];
    const float* ln_b  = (const float*)d_in[13];
    const float* Wlm   = (const float*)d_in[14];
    const float* blm   = (const float*)d_in[15];
    float* out = (float*)d_out;

    char* ws = (char*)d_ws;
    ushort* wqkvT = (ushort*)(ws);                 //  9,437,184
    ushort* woT   = (ushort*)(ws + 9437184);       //  3,145,728
    ushort* x0    = (ushort*)(ws + 12582912);      //  1,703,936
    float*  lu    = (float*) (ws + 14286848);      //     86,528

    prep_all<<<1952, 256, 0, stream>>>(Wq, Wk, Wv, Wo, wte, wpe, wqkvT, woT, x0);
    net_kernel<<<104, 512, 0, stream>>>(x0, wqkvT, woT, bq, bk, bv, bo,
                                        ln_g, ln_b, Wlm, blm, lu);
    scatter_loss<<<3329, 256, 0, stream>>>(lu, tok, label, out);
}

// Round 12
// 254.253 us; speedup vs baseline: 1.1740x; 1.1740x over previous
//
#include <hip/hip_runtime.h>
#include <hip/hip_bf16.h>
#include <cstdint>
#include <cstddef>

// ---------------------------------------------------------------------------
// Transformer_78941498901000 — round 11: back to the measured-best r8
// pipeline (many short parallel dispatches), with stage-count cut by proven
// fusions only: prep+x0 merged; attn fused into proj (B-stage overlaps attn,
// tmp gets own buffer); final LN folded into logits; scatter+loss merged.
// Dedup (r7): rows depend only on (token, position) => U = 13*128 = 1664.
// 20 dispatches (r8 had 29 at 228 us; r10 persistent = 298 us).
// d_out = logits f32 [851968] ++ loss f32 [1]
//
// ws layout (bytes), ~21.2 MB:
//   xbf   @ 0          : bf16 [1664,512]      1,703,936  (LN'd residual stream)
//   wqkvT @ 1,703,936  : bf16 [L][1536][512]  9,437,184  (n-major, k-minor)
//   woT   @ 11,141,120 : bf16 [L][512][512]   3,145,728
//   qkv_u @ 14,286,848 : bf16 [1664,1536]     5,111,808
//   tmp   @ 19,398,656 : bf16 [1664,512]      1,703,936  (pre-LN out)
//   lu    @ 21,102,592 : f32  [1664,13]          86,528
//   ps    @ 21,189,120 : f32  [4][1664]          26,624
//   pss   @ 21,215,744 : f32  [4][1664]          26,624
// ---------------------------------------------------------------------------

typedef __attribute__((ext_vector_type(8))) short short8;
typedef __attribute__((ext_vector_type(4))) float f32x4;

__device__ __forceinline__ float bf2f(ushort u) {
    return __uint_as_float(((unsigned int)u) << 16);
}
__device__ __forceinline__ ushort f2bf(float f) {
    unsigned int x = __float_as_uint(f);
    unsigned int r = (x + 0x7fffu + ((x >> 16) & 1u)) >> 16;  // RNE
    return (ushort)r;
}
__device__ __forceinline__ void gload_lds16(const void* g, void* l) {
    __builtin_amdgcn_global_load_lds(
        (const __attribute__((address_space(1))) void*)g,
        (__attribute__((address_space(3))) void*)l, 16, 0, 0);
}

// ---------------- prep: weight transpose + x0 -------------------------------
__global__ __launch_bounds__(256) void prep_all(
    const float* __restrict__ Wq, const float* __restrict__ Wk,
    const float* __restrict__ Wv, const float* __restrict__ Wo,
    const float* __restrict__ wte, const float* __restrict__ wpe,
    ushort* __restrict__ wqkvT, ushort* __restrict__ woT,
    ushort* __restrict__ x0) {
    __shared__ float lds[64][65];
    const int bid = blockIdx.x;
    const int tid = threadIdx.x;
    if (bid < 1536) {                      // 24 matrices x 64 tiles of 64x64
        const int mat = bid >> 6;
        const int tile = bid & 63;
        const int tr = tile >> 3, tc = tile & 7;
        const int l = mat >> 2, which = mat & 3;
        const float* S;
        switch (which) {
            case 0: S = Wq; break;
            case 1: S = Wk; break;
            case 2: S = Wv; break;
            default: S = Wo; break;
        }
        S += (size_t)l * 262144;
        ushort* T = (which < 3) ? wqkvT + (size_t)l * 786432 + which * 262144
                                : woT + (size_t)l * 262144;
        const int c = tid & 63;
        #pragma unroll
        for (int it = 0; it < 16; it++) {
            int r = it * 4 + (tid >> 6);
            lds[r][c] = S[(size_t)(tr * 64 + r) * 512 + tc * 64 + c];
        }
        __syncthreads();
        #pragma unroll
        for (int it = 0; it < 16; it++) {
            int r = it * 4 + (tid >> 6);
            T[(size_t)(tc * 64 + r) * 512 + tr * 64 + c] = f2bf(lds[c][r]);
        }
    } else {                               // x0 = wte[v] + wpe[t]
        size_t idx = (size_t)(bid - 1536) * 256 + tid;
        size_t u = idx >> 6;               // < 1664
        int c8 = (int)(idx & 63);
        int v = (int)(u >> 7);
        int t = (int)(u & 127);
        const float* ep = wte + (size_t)v * 512 + c8 * 8;
        const float* pp = wpe + (size_t)t * 512 + c8 * 8;
        float4 e0 = *(const float4*)ep, e1 = *(const float4*)(ep + 4);
        float4 p0 = *(const float4*)pp, p1 = *(const float4*)(pp + 4);
        float s[8] = {e0.x + p0.x, e0.y + p0.y, e0.z + p0.z, e0.w + p0.w,
                      e1.x + p1.x, e1.y + p1.y, e1.z + p1.z, e1.w + p1.w};
        short8 o;
        #pragma unroll
        for (int j = 0; j < 8; j++) o[j] = (short)f2bf(s[j]);
        *(short8*)(x0 + u * 512 + c8 * 8) = o;
    }
}

// ---------------- QKV GEMM: qkv = A[1664,512] @ Bt[1536,512]^T + bias ------
// BM=64, BN=128, BK=64, 4 waves (wave tile 32x64), double-buffered
// global_load_lds, XOR-swizzled LDS. grid (26, 12). (r8 verbatim, 228us cfg)
__global__ __launch_bounds__(256) void gemm_qkv_kernel(
    const ushort* __restrict__ A, const ushort* __restrict__ Bt,
    const float* __restrict__ b0, const float* __restrict__ b1,
    const float* __restrict__ b2, ushort* __restrict__ obf) {
    __shared__ alignas(16) ushort As[2][64 * 64];    // 2 x 8 KB
    __shared__ alignas(16) ushort Bs[2][128 * 64];   // 2 x 16 KB
    const int tid = threadIdx.x;
    const int lane = tid & 63;
    const int wave = tid >> 6;
    const int m0 = blockIdx.x * 64;
    const int n0 = blockIdx.y * 128;
    const int wm = (wave >> 1) * 32;
    const int wn = (wave & 1) * 64;
    const int r = lane & 15;
    const int kq = (lane >> 4) * 8;
    const ushort* Ab = A  + (size_t)m0 * 512;
    const ushort* Bb = Bt + (size_t)n0 * 512;
    f32x4 acc[2][4] = {};

    auto stage = [&](int t, int b) {
        const ushort* At = Ab + t * 64;
        const ushort* Bt2 = Bb + t * 64;
        #pragma unroll
        for (int i = 0; i < 2; i++) {                // A: 512 chunks
            int cb = (i * 4 + wave) * 64;
            int ch = cb + lane;
            int row = ch >> 3;
            int c8 = (ch & 7) ^ (row & 7);
            gload_lds16(At + (size_t)row * 512 + c8 * 8, (char*)As[b] + cb * 16);
        }
        #pragma unroll
        for (int i = 0; i < 4; i++) {                // B: 1024 chunks
            int cb = (i * 4 + wave) * 64;
            int ch = cb + lane;
            int row = ch >> 3;
            int c8 = (ch & 7) ^ (row & 7);
            gload_lds16(Bt2 + (size_t)row * 512 + c8 * 8, (char*)Bs[b] + cb * 16);
        }
    };

    stage(0, 0);
    __syncthreads();
    #pragma unroll
    for (int t = 0; t < 8; t++) {
        const int cur = t & 1;
        if (t < 7) stage(t + 1, cur ^ 1);            // prefetch next tile
        #pragma unroll
        for (int kk = 0; kk < 64; kk += 32) {
            short8 af[2], bfr[4];
            #pragma unroll
            for (int m = 0; m < 2; m++) {
                int row = wm + m * 16 + r;
                int boff = (row * 128 + (kk + kq) * 2) ^ ((row & 7) << 4);
                af[m] = *(const short8*)((const char*)As[cur] + boff);
            }
            #pragma unroll
            for (int n = 0; n < 4; n++) {
                int row = wn + n * 16 + r;
                int boff = (row * 128 + (kk + kq) * 2) ^ ((row & 7) << 4);
                bfr[n] = *(const short8*)((const char*)Bs[cur] + boff);
            }
            #pragma unroll
            for (int m = 0; m < 2; m++)
                #pragma unroll
                for (int n = 0; n < 4; n++)
                    acc[m][n] = __builtin_amdgcn_mfma_f32_16x16x32_bf16(
                        af[m], bfr[n], acc[m][n], 0, 0, 0);
        }
        __syncthreads();
    }
    const int r4 = (lane >> 4) * 4;
    const int cc = lane & 15;
    #pragma unroll
    for (int m = 0; m < 2; m++) {
        #pragma unroll
        for (int n = 0; n < 4; n++) {
            int cg = n0 + wn + n * 16 + cc;
            float bias = (cg < 512) ? b0[cg] : (cg < 1024) ? b1[cg - 512] : b2[cg - 1024];
            #pragma unroll
            for (int i = 0; i < 4; i++) {
                int rg = m0 + wm + m * 16 + r4 + i;
                obf[(size_t)rg * 1536 + cg] = f2bf(acc[m][n][i] + bias);
            }
        }
    }
}

// ---------------- fused attn + proj + bias + residual + partial stats ------
// Block: 32 rows x 128 cols, 256 thr (4 waves). Phase 1: head-axis attention
// for the 32 rows -> Hs (8 subtiles [32][64], XOR-swizzled); Bs(0) staged
// BEFORE attn so its latency overlaps. Phase 2: GEMM vs woT (B gload dbuf).
// Epilogue: v = acc + bo + xres (r8 semantics); tmp=bf16(v); stats -> ps/pss.
__global__ __launch_bounds__(256) void attn_proj(
    const ushort* __restrict__ qkv, const ushort* __restrict__ Bt,
    const float* __restrict__ bo_, const ushort* __restrict__ xres,
    ushort* __restrict__ tmp, float* __restrict__ ps, float* __restrict__ pss) {
    __shared__ alignas(16) ushort Hs[8][32 * 64];    // 32 KB
    __shared__ alignas(16) ushort Bs[2][128 * 64];   // 32 KB
    __shared__ float lps[2][32], lpss[2][32];
    const int tid = threadIdx.x;
    const int lane = tid & 63;
    const int wave = tid >> 6;            // 0..3
    const int m0 = blockIdx.x * 32;
    const int n0 = blockIdx.y * 128;

    const ushort* Bb = Bt + (size_t)n0 * 512;
    auto stageB = [&](int t, int b) {
        const ushort* Bt2 = Bb + t * 64;
        #pragma unroll
        for (int i = 0; i < 4; i++) {
            int cb = (i * 4 + wave) * 64;
            int ch = cb + lane;
            int row = ch >> 3;
            int c8 = (ch & 7) ^ (row & 7);
            gload_lds16(Bt2 + (size_t)row * 512 + c8 * 8, (char*)Bs[b] + cb * 16);
        }
    };
    stageB(0, 0);                          // overlap B(0) with attention

    {   // ---- attention: 8 rows per wave -> Hs ----
        const int h = lane >> 3, g = lane & 7;
        #pragma unroll
        for (int it = 0; it < 8; it++) {
            int lrow = wave * 8 + it;
            const ushort* base = qkv + (size_t)(m0 + lrow) * 1536;
            const ushort* qp = base + h * 64;
            const ushort* kp = base + 512 + g * 64;
            float s = 0.f;
            #pragma unroll
            for (int dc = 0; dc < 8; dc++) {
                short8 q8 = *(const short8*)(qp + dc * 8);
                short8 k8 = *(const short8*)(kp + dc * 8);
                #pragma unroll
                for (int j = 0; j < 8; j++) s += bf2f((ushort)q8[j]) * bf2f((ushort)k8[j]);
            }
            s *= 0.125f;
            float mx = s;
            #pragma unroll
            for (int o = 1; o < 8; o <<= 1) mx = fmaxf(mx, __shfl_xor(mx, o));
            float e = __expf(s - mx);
            float den = e;
            #pragma unroll
            for (int o = 1; o < 8; o <<= 1) den += __shfl_xor(den, o);
            float att = e / den;
            float o8[8];
            #pragma unroll
            for (int j = 0; j < 8; j++) o8[j] = 0.f;
            const ushort* vp = base + 1024 + (lane & 7) * 8;
            #pragma unroll
            for (int gg = 0; gg < 8; gg++) {
                float a = __shfl(att, (lane & 56) | gg);
                short8 v8 = *(const short8*)(vp + gg * 64);
                #pragma unroll
                for (int j = 0; j < 8; j++) o8[j] += a * bf2f((ushort)v8[j]);
            }
            short8 ov;
            #pragma unroll
            for (int j = 0; j < 8; j++) ov[j] = (short)f2bf(o8[j]);
            int off = (lrow * 128 + (lane & 7) * 16) ^ ((lrow & 7) << 4);
            *(short8*)((char*)Hs[lane >> 3] + off) = ov;
        }
    }
    __syncthreads();                       // Hs ready, B(0) drained

    // ---- GEMM: 8 k-subtiles, A from Hs[t], B dbuf ----
    const int r = lane & 15;
    const int kq = (lane >> 4) * 8;
    const int wm = (wave >> 1) * 16;       // 0 | 16
    const int wn = (wave & 1) * 64;        // 0 | 64
    f32x4 acc[4] = {};
    #pragma unroll
    for (int t = 0; t < 8; t++) {
        const int cur = t & 1;
        if (t < 7) stageB(t + 1, cur ^ 1);
        #pragma unroll
        for (int kk = 0; kk < 64; kk += 32) {
            int arow = wm + r;
            int aoff = (arow * 128 + (kk + kq) * 2) ^ ((arow & 7) << 4);
            short8 af = *(const short8*)((const char*)Hs[t] + aoff);
            #pragma unroll
            for (int n = 0; n < 4; n++) {
                int brow = wn + n * 16 + r;
                int boff = (brow * 128 + (kk + kq) * 2) ^ ((brow & 7) << 4);
                short8 bfr = *(const short8*)((const char*)Bs[cur] + boff);
                acc[n] = __builtin_amdgcn_mfma_f32_16x16x32_bf16(
                    af, bfr, acc[n], 0, 0, 0);
            }
        }
        __syncthreads();
    }

    // ---- epilogue: v = acc + bo + xres; tmp=bf16(v); partial row stats ----
    const int r4 = (lane >> 4) * 4;
    const int cc = lane & 15;
    float s_i[4] = {0.f, 0.f, 0.f, 0.f}, ss_i[4] = {0.f, 0.f, 0.f, 0.f};
    #pragma unroll
    for (int n = 0; n < 4; n++) {
        int col = n0 + wn + n * 16 + cc;
        float bias = bo_[col];
        #pragma unroll
        for (int i = 0; i < 4; i++) {
            int rg = m0 + wm + r4 + i;
            float v = acc[n][i] + bias + bf2f(xres[(size_t)rg * 512 + col]);
            tmp[(size_t)rg * 512 + col] = f2bf(v);
            s_i[i] += v; ss_i[i] += v * v;
        }
    }
    #pragma unroll
    for (int i = 0; i < 4; i++) {
        #pragma unroll
        for (int o = 1; o < 16; o <<= 1) {
            s_i[i] += __shfl_xor(s_i[i], o);
            ss_i[i] += __shfl_xor(ss_i[i], o);
        }
    }
    if (cc == 0) {
        #pragma unroll
        for (int i = 0; i < 4; i++) {
            lps[wave & 1][wm + r4 + i] = s_i[i];
            lpss[wave & 1][wm + r4 + i] = ss_i[i];
        }
    }
    __syncthreads();
    if (tid < 32) {
        int row = m0 + tid;
        ps[blockIdx.y * 1664 + row]  = lps[0][tid] + lps[1][tid];
        pss[blockIdx.y * 1664 + row] = lpss[0][tid] + lpss[1][tid];
    }
}

// ---------------- LN finalize: xbf = bf16(LN(tmp)) (r8 verbatim) -----------
__global__ __launch_bounds__(256) void ln_finalize_kernel(
    const ushort* __restrict__ tmp, const float* __restrict__ ps,
    const float* __restrict__ pss, const float* __restrict__ gw,
    const float* __restrict__ bw, ushort* __restrict__ xbf) {
    const int lane = threadIdx.x & 63;
    const size_t row = (size_t)blockIdx.x * 4 + (threadIdx.x >> 6);
    float s  = ps[row]  + ps[1664 + row]  + ps[2 * 1664 + row]  + ps[3 * 1664 + row];
    float ss = pss[row] + pss[1664 + row] + pss[2 * 1664 + row] + pss[3 * 1664 + row];
    float mean = s * (1.f / 512.f);
    float var = ss * (1.f / 512.f) - mean * mean;
    float rstd = rsqrtf(var + 1e-5f);
    short8 tv = *(const short8*)(tmp + row * 512 + lane * 8);
    const float* gp = gw + lane * 8;
    const float* bp = bw + lane * 8;
    float4 g0 = *(const float4*)gp, g1 = *(const float4*)(gp + 4);
    float4 b0 = *(const float4*)bp, b1 = *(const float4*)(bp + 4);
    float gg[8] = {g0.x, g0.y, g0.z, g0.w, g1.x, g1.y, g1.z, g1.w};
    float bb[8] = {b0.x, b0.y, b0.z, b0.w, b1.x, b1.y, b1.z, b1.w};
    short8 o;
    #pragma unroll
    for (int j = 0; j < 8; j++)
        o[j] = (short)f2bf((bf2f((ushort)tv[j]) - mean) * rstd * gg[j] + bb[j]);
    *(short8*)(xbf + row * 512 + lane * 8) = o;
}

// ---------------- logits with final LN inline (r9 verbatim) ----------------
__global__ __launch_bounds__(256) void logits_ln(
    const ushort* __restrict__ tin, const float* __restrict__ psin,
    const float* __restrict__ pssin, const float* __restrict__ gv,
    const float* __restrict__ bv, const float* __restrict__ Wlm,
    const float* __restrict__ blm, float* __restrict__ lu) {
    __shared__ float wl[8 * 64 * 13];
    const int tid = threadIdx.x;
    for (int k = tid; k < 512; k += 256) {
        int dst = ((k & 7) * 64 + (k >> 3)) * 13;
        #pragma unroll
        for (int v = 0; v < 13; v++) wl[dst + v] = Wlm[k * 13 + v];
    }
    __syncthreads();
    const int lane = tid & 63;
    const int w = tid >> 6;
    const int c0 = lane * 8;
    float4 g0 = *(const float4*)(gv + c0), g1 = *(const float4*)(gv + c0 + 4);
    float4 b0 = *(const float4*)(bv + c0), b1 = *(const float4*)(bv + c0 + 4);
    float gg[8] = {g0.x, g0.y, g0.z, g0.w, g1.x, g1.y, g1.z, g1.w};
    float bb[8] = {b0.x, b0.y, b0.z, b0.w, b1.x, b1.y, b1.z, b1.w};
    float bl[13];
    #pragma unroll
    for (int v = 0; v < 13; v++) bl[v] = blm[v];
    for (int it = 0; it < 8; it++) {
        size_t row = (size_t)blockIdx.x * 32 + it * 4 + w;   // < 1664
        float s  = psin[row] + psin[1664 + row] + psin[3328 + row] + psin[4992 + row];
        float ss = pssin[row] + pssin[1664 + row] + pssin[3328 + row] + pssin[4992 + row];
        float mean = s * (1.f / 512.f);
        float rstd = rsqrtf(ss * (1.f / 512.f) - mean * mean + 1e-5f);
        short8 xv = *(const short8*)(tin + row * 512 + c0);
        float p[13];
        #pragma unroll
        for (int v = 0; v < 13; v++) p[v] = 0.f;
        #pragma unroll
        for (int j = 0; j < 8; j++) {
            float xf = (bf2f((ushort)xv[j]) - mean) * rstd * gg[j] + bb[j];
            const float* wr = wl + (j * 64 + lane) * 13;
            #pragma unroll
            for (int v = 0; v < 13; v++) p[v] += xf * wr[v];
        }
        #pragma unroll
        for (int v = 0; v < 13; v++) {
            #pragma unroll
            for (int o = 32; o > 0; o >>= 1) p[v] += __shfl_xor(p[v], o);
        }
        if (lane == 0) {
            #pragma unroll
            for (int v = 0; v < 13; v++) lu[row * 13 + v] = p[v] + bl[v];
        }
    }
}

// ---------------- scatter + loss (merged, proven) ---------------------------
__global__ __launch_bounds__(256) void scatter_loss(
    const float* __restrict__ lu, const int* __restrict__ tok,
    const int* __restrict__ label, float* __restrict__ out) {
    __shared__ float red[4];
    const int tid = threadIdx.x;
    if (blockIdx.x < 3328) {
        unsigned int i = blockIdx.x * 256 + tid;      // < 851968 exactly
        unsigned int bt = i / 13u;
        unsigned int vv = i - bt * 13u;
        int v = tok[bt];
        int t = (int)(bt & 127u);
        out[i] = lu[(size_t)((v << 7) + t) * 13 + vv];
    } else {
        float acc = 0.f;
        for (int b = tid; b < 512; b += 256) {
            int v = tok[b * 128 + 127];
            const float* lg = lu + (size_t)((v << 7) + 127) * 13;
            float mx = lg[0];
            #pragma unroll
            for (int vv = 1; vv < 13; vv++) mx = fmaxf(mx, lg[vv]);
            float den = 0.f;
            #pragma unroll
            for (int vv = 0; vv < 13; vv++) den += expf(lg[vv] - mx);
            int lab = label[b];
            acc += -(lg[lab] - mx - logf(den));
        }
        #pragma unroll
        for (int o = 32; o > 0; o >>= 1) acc += __shfl_xor(acc, o);
        if ((tid & 63) == 0) red[tid >> 6] = acc;
        __syncthreads();
        if (tid == 0)
            out[851968] = (red[0] + red[1] + red[2] + red[3]) * (1.f / 512.f);
    }
}

// ---------------------------------------------------------------------------
extern "C" void kernel_launch(void* const* d_in, const int* in_sizes, int n_in,
                              void* d_out, int out_size, void* d_ws, size_t ws_size,
                              hipStream_t stream) {
    const int*   tok   = (const int*)d_in[0];
    const int*   label = (const int*)d_in[1];
    const float* wte   = (const float*)d_in[2];
    const float* wpe   = (const float*)d_in[3];
    const float* Wq    = (const float*)d_in[4];
    const float* bq    = (const float*)d_in[5];
    const float* Wk    = (const float*)d_in[6];
    const float* bk    = (const float*)d_in[7];
    const float* Wv    = (const float*)d_in[8];
    const float* bv    = (const float*)d_in[9];
    const float* Wo    = (const float*)d_in[10];
    const float* bo    = (const float*)d_in[11];
    const float* ln_g  = (const float*)d_in[12];
    const float* ln_b  = (const float*)d_in[13];
    const float* Wlm   = (const float*)d_in[14];
    const float* blm   = (const float*)d_in[15];
    float* out = (float*)d_out;

    char* ws = (char*)d_ws;
    ushort* xbf   = (ushort*)(ws);                 //  1,703,936
    ushort* wqkvT = (ushort*)(ws + 1703936);       //  9,437,184
    ushort* woT   = (ushort*)(ws + 11141120);      //  3,145,728
    ushort* qkv_u = (ushort*)(ws + 14286848);      //  5,111,808
    ushort* tmp   = (ushort*)(ws + 19398656);      //  1,703,936
    float*  lu    = (float*) (ws + 21102592);      //     86,528
    float*  ps    = (float*) (ws + 21189120);      //     26,624
    float*  pss   = (float*) (ws + 21215744);      //     26,624

    prep_all<<<1952, 256, 0, stream>>>(Wq, Wk, Wv, Wo, wte, wpe, wqkvT, woT, xbf);

    for (int l = 0; l < 6; l++) {
        gemm_qkv_kernel<<<dim3(26, 12), 256, 0, stream>>>(
            xbf, wqkvT + (size_t)l * 786432,
            bq + l * 512, bk + l * 512, bv + l * 512, qkv_u);
        attn_proj<<<dim3(52, 4), 256, 0, stream>>>(
            qkv_u, woT + (size_t)l * 262144, bo + l * 512, xbf, tmp, ps, pss);
        if (l < 5)
            ln_finalize_kernel<<<416, 256, 0, stream>>>(
                tmp, ps, pss, ln_g + l * 512, ln_b + l * 512, xbf);
    }

    logits_ln<<<52, 256, 0, stream>>>(tmp, ps, pss,
                                      ln_g + 5 * 512, ln_b + 5 * 512, Wlm, blm, lu);
    scatter_loss<<<3329, 256, 0, stream>>>(lu, tok, label, out);
}

// Round 13
// 220.385 us; speedup vs baseline: 1.3544x; 1.1537x over previous
//
#include <hip/hip_runtime.h>
#include <hip/hip_bf16.h>
#include <cstdint>
#include <cstddef>

// ---------------------------------------------------------------------------
// Transformer_78941498901000 — round 12: r8 pipeline + LN folded into weights.
// Dedup (r7): rows depend only on (token, position) => U = 13*128 = 1664.
// LN(x)@W = r*(x@W') - r*mu*s + t  with W' = g.W, s_n = sum_k W'_kn,
// t_n = sum_k b_k W_kn  (precomputed in prep). qkv GEMM reads the raw pre-LN
// residual tmp; per-row (mu,r) from ps/pss applied in the epilogue only.
// Deletes all 6 ln_finalize dispatches. 21 dispatches (r8: 29 @ 228us).
// d_out = logits f32 [851968] ++ loss f32 [1]
//
// ws layout (bytes), ~21.4 MB:
//   wqkvT @ 0          : bf16 [L][1536][512]  9,437,184  (g-folded, n-major)
//   woT   @ 9,437,184  : bf16 [L][512][512]   3,145,728  (raw, n-major)
//   qkv_u @ 12,582,912 : bf16 [1664,1536]     5,111,808
//   hid_u @ 17,694,720 : bf16 [1664,512]      1,703,936
//   tmp   @ 19,398,656 : bf16 [1664,512]      1,703,936  (pre-LN residual)
//   psA/pssA/psB/pssB @ 21,102,592 : f32 [4][1664] x4       106,496
//   lu    @ 21,209,088 : f32  [1664,13]          86,528
//   s_qkv @ 21,295,616 : f32  [L][1536]          36,864
//   t_qkv @ 21,332,480 : f32  [L][1536]          36,864
//   ones  @ 21,369,344 : f32 [512]; zeros @ 21,371,392 : f32 [512]
// ---------------------------------------------------------------------------

typedef __attribute__((ext_vector_type(8))) short short8;
typedef __attribute__((ext_vector_type(4))) float f32x4;

__device__ __forceinline__ float bf2f(ushort u) {
    return __uint_as_float(((unsigned int)u) << 16);
}
__device__ __forceinline__ ushort f2bf(float f) {
    unsigned int x = __float_as_uint(f);
    unsigned int r = (x + 0x7fffu + ((x >> 16) & 1u)) >> 16;  // RNE
    return (ushort)r;
}
__device__ __forceinline__ void gload_lds16(const void* g, void* l) {
    __builtin_amdgcn_global_load_lds(
        (const __attribute__((address_space(1))) void*)g,
        (__attribute__((address_space(3))) void*)l, 16, 0, 0);
}

// ---------------- prep: folded transpose + s/t + x0 + stats-init -----------
__global__ __launch_bounds__(256) void prep_all(
    const float* __restrict__ Wq, const float* __restrict__ Wk,
    const float* __restrict__ Wv, const float* __restrict__ Wo,
    const float* __restrict__ wte, const float* __restrict__ wpe,
    const float* __restrict__ ln_g, const float* __restrict__ ln_b,
    ushort* __restrict__ wqkvT, ushort* __restrict__ woT,
    ushort* __restrict__ tmp0, float* __restrict__ s_qkv,
    float* __restrict__ t_qkv, float* __restrict__ psA,
    float* __restrict__ pssA, float* __restrict__ ones,
    float* __restrict__ zeros) {
    __shared__ float lds[64][65];
    __shared__ float gld[64], bld[64];
    __shared__ float sred[4][64], tred[4][64];
    const int bid = blockIdx.x;
    const int tid = threadIdx.x;
    if (bid < 192) {                       // 24 matrices x 8 column strips
        const int mat = bid >> 3;
        const int tc = bid & 7;
        const int l = mat >> 2, which = mat & 3;
        const float* S;
        switch (which) {
            case 0: S = Wq; break;
            case 1: S = Wk; break;
            case 2: S = Wv; break;
            default: S = Wo; break;
        }
        S += (size_t)l * 262144;
        ushort* T = (which < 3) ? wqkvT + (size_t)l * 786432 + which * 262144
                                : woT + (size_t)l * 262144;
        const bool fold = (which < 3);
        const float* g = (fold && l > 0) ? ln_g + (l - 1) * 512 : nullptr;
        const float* b = (fold && l > 0) ? ln_b + (l - 1) * 512 : nullptr;
        const int c = tid & 63;
        float sp = 0.f, tp = 0.f;
        for (int tr = 0; tr < 8; tr++) {
            __syncthreads();
            #pragma unroll
            for (int it = 0; it < 16; it++) {
                int r = it * 4 + (tid >> 6);
                lds[r][c] = S[(size_t)(tr * 64 + r) * 512 + tc * 64 + c];
            }
            if (tid < 64) {
                gld[tid] = g ? g[tr * 64 + tid] : 1.f;
                bld[tid] = b ? b[tr * 64 + tid] : 0.f;
            }
            __syncthreads();
            // transpose-write (k = tr*64 + c fixed per thread), fold by g[k]
            float gk = fold ? gld[c] : 1.f;
            #pragma unroll
            for (int it = 0; it < 16; it++) {
                int rn = it * 4 + (tid >> 6);          // n_local
                float val = lds[c][rn] * gk;           // W[k][n] * g[k]
                T[(size_t)(tc * 64 + rn) * 512 + tr * 64 + c] = f2bf(val);
            }
            if (fold) {   // s/t partials: thread owns n_local=c, k-chunk=tid>>6
                #pragma unroll
                for (int i = 0; i < 16; i++) {
                    int kl = (tid >> 6) * 16 + i;
                    float w = lds[kl][c];              // W[k][n_local]
                    sp += gld[kl] * w;
                    tp += bld[kl] * w;
                }
            }
        }
        if (fold) {
            __syncthreads();
            sred[tid >> 6][c] = sp;
            tred[tid >> 6][c] = tp;
            __syncthreads();
            if (tid < 64) {
                float ss = sred[0][tid] + sred[1][tid] + sred[2][tid] + sred[3][tid];
                float tt = tred[0][tid] + tred[1][tid] + tred[2][tid] + tred[3][tid];
                int o = l * 1536 + which * 512 + tc * 64 + tid;
                s_qkv[o] = ss;
                t_qkv[o] = tt;
            }
        }
    } else if (bid < 608) {                // x0 = wte[v] + wpe[t] -> tmp
        size_t idx = (size_t)(bid - 192) * 256 + tid;
        size_t u = idx >> 6;               // < 1664
        int c8 = (int)(idx & 63);
        int v = (int)(u >> 7);
        int t = (int)(u & 127);
        const float* ep = wte + (size_t)v * 512 + c8 * 8;
        const float* pp = wpe + (size_t)t * 512 + c8 * 8;
        float4 e0 = *(const float4*)ep, e1 = *(const float4*)(ep + 4);
        float4 p0 = *(const float4*)pp, p1 = *(const float4*)(pp + 4);
        float s[8] = {e0.x + p0.x, e0.y + p0.y, e0.z + p0.z, e0.w + p0.w,
                      e1.x + p1.x, e1.y + p1.y, e1.z + p1.z, e1.w + p1.w};
        short8 o;
        #pragma unroll
        for (int j = 0; j < 8; j++) o[j] = (short)f2bf(s[j]);
        *(short8*)(tmp0 + u * 512 + c8 * 8) = o;
    } else if (bid < 660) {                // identity stats: mu=0, rstd=1
        int i = (bid - 608) * 256 + tid;   // < 13312
        if (i < 6656) psA[i] = 0.f;
        else {
            int j = i - 6656;
            pssA[j] = (j < 1664) ? 511.99488f : 0.f;
        }
    } else {                               // identity LN tables for layer 0
        ones[tid] = 1.f;  ones[tid + 256] = 1.f;
        zeros[tid] = 0.f; zeros[tid + 256] = 0.f;
    }
}

// ---------------- QKV GEMM on raw residual + folded-LN epilogue ------------
// obf = r*(tmp @ W'^T) - r*mu*s + t + bias. BM=64, BN=128, BK=64, 4 waves,
// double-buffered global_load_lds (r8-proven core). grid (26, 12).
__global__ __launch_bounds__(256) void qkv_fold(
    const ushort* __restrict__ A, const float* __restrict__ psin,
    const float* __restrict__ pssin, const ushort* __restrict__ Bt,
    const float* __restrict__ s_l, const float* __restrict__ t_l,
    const float* __restrict__ b0, const float* __restrict__ b1,
    const float* __restrict__ b2, ushort* __restrict__ obf) {
    __shared__ alignas(16) ushort As[2][64 * 64];    // 2 x 8 KB
    __shared__ alignas(16) ushort Bs[2][128 * 64];   // 2 x 16 KB
    __shared__ float smu[64], srs[64];
    const int tid = threadIdx.x;
    const int lane = tid & 63;
    const int wave = tid >> 6;
    const int m0 = blockIdx.x * 64;
    const int n0 = blockIdx.y * 128;
    const int wm = (wave >> 1) * 32;
    const int wn = (wave & 1) * 64;
    const int r = lane & 15;
    const int kq = (lane >> 4) * 8;
    const ushort* Ab = A  + (size_t)m0 * 512;
    const ushort* Bb = Bt + (size_t)n0 * 512;
    f32x4 acc[2][4] = {};

    auto stage = [&](int t, int b) {
        const ushort* At = Ab + t * 64;
        const ushort* Bt2 = Bb + t * 64;
        #pragma unroll
        for (int i = 0; i < 2; i++) {                // A: 512 chunks
            int cb = (i * 4 + wave) * 64;
            int ch = cb + lane;
            int row = ch >> 3;
            int c8 = (ch & 7) ^ (row & 7);
            gload_lds16(At + (size_t)row * 512 + c8 * 8, (char*)As[b] + cb * 16);
        }
        #pragma unroll
        for (int i = 0; i < 4; i++) {                // B: 1024 chunks
            int cb = (i * 4 + wave) * 64;
            int ch = cb + lane;
            int row = ch >> 3;
            int c8 = (ch & 7) ^ (row & 7);
            gload_lds16(Bt2 + (size_t)row * 512 + c8 * 8, (char*)Bs[b] + cb * 16);
        }
    };

    stage(0, 0);
    if (tid < 64) {                        // per-row LN stats (overlaps stage)
        int row = m0 + tid;
        float s  = psin[row] + psin[1664 + row] + psin[3328 + row] + psin[4992 + row];
        float ss = pssin[row] + pssin[1664 + row] + pssin[3328 + row] + pssin[4992 + row];
        float mean = s * (1.f / 512.f);
        float var = ss * (1.f / 512.f) - mean * mean;
        smu[tid] = mean;
        srs[tid] = rsqrtf(var + 1e-5f);
    }
    __syncthreads();
    #pragma unroll
    for (int t = 0; t < 8; t++) {
        const int cur = t & 1;
        if (t < 7) stage(t + 1, cur ^ 1);            // prefetch next tile
        #pragma unroll
        for (int kk = 0; kk < 64; kk += 32) {
            short8 af[2], bfr[4];
            #pragma unroll
            for (int m = 0; m < 2; m++) {
                int row = wm + m * 16 + r;
                int boff = (row * 128 + (kk + kq) * 2) ^ ((row & 7) << 4);
                af[m] = *(const short8*)((const char*)As[cur] + boff);
            }
            #pragma unroll
            for (int n = 0; n < 4; n++) {
                int row = wn + n * 16 + r;
                int boff = (row * 128 + (kk + kq) * 2) ^ ((row & 7) << 4);
                bfr[n] = *(const short8*)((const char*)Bs[cur] + boff);
            }
            #pragma unroll
            for (int m = 0; m < 2; m++)
                #pragma unroll
                for (int n = 0; n < 4; n++)
                    acc[m][n] = __builtin_amdgcn_mfma_f32_16x16x32_bf16(
                        af[m], bfr[n], acc[m][n], 0, 0, 0);
        }
        __syncthreads();
    }
    const int r4 = (lane >> 4) * 4;
    const int cc = lane & 15;
    #pragma unroll
    for (int m = 0; m < 2; m++) {
        #pragma unroll
        for (int n = 0; n < 4; n++) {
            int cg = n0 + wn + n * 16 + cc;
            float bias = (cg < 512) ? b0[cg] : (cg < 1024) ? b1[cg - 512] : b2[cg - 1024];
            float sc = s_l[cg];
            float tc_ = t_l[cg] + bias;
            #pragma unroll
            for (int i = 0; i < 4; i++) {
                int lrow = wm + m * 16 + r4 + i;
                float v = srs[lrow] * (acc[m][n][i] - smu[lrow] * sc) + tc_;
                obf[(size_t)(m0 + lrow) * 1536 + cg] = f2bf(v);
            }
        }
    }
}

// ---------------- per-position head-axis attention (r8 verbatim) -----------
__global__ __launch_bounds__(256) void attn_kernel(const ushort* __restrict__ qkv,
                                                   ushort* __restrict__ hid) {
    const int lane = threadIdx.x & 63;
    const size_t pos = (size_t)blockIdx.x * 4 + (threadIdx.x >> 6);
    const ushort* base = qkv + pos * 1536;
    const int h = lane >> 3, g = lane & 7;
    const ushort* qp = base + h * 64;
    const ushort* kp = base + 512 + g * 64;
    float s = 0.f;
    #pragma unroll
    for (int dc = 0; dc < 8; dc++) {
        short8 q8 = *(const short8*)(qp + dc * 8);
        short8 k8 = *(const short8*)(kp + dc * 8);
        #pragma unroll
        for (int j = 0; j < 8; j++) s += bf2f((ushort)q8[j]) * bf2f((ushort)k8[j]);
    }
    s *= 0.125f;  // 1/sqrt(64)
    float mx = s;
    #pragma unroll
    for (int o = 1; o < 8; o <<= 1) mx = fmaxf(mx, __shfl_xor(mx, o));
    float e = __expf(s - mx);
    float den = e;
    #pragma unroll
    for (int o = 1; o < 8; o <<= 1) den += __shfl_xor(den, o);
    float att = e / den;
    float o8[8];
    #pragma unroll
    for (int j = 0; j < 8; j++) o8[j] = 0.f;
    const ushort* vp = base + 1024 + (lane & 7) * 8;
    #pragma unroll
    for (int gg = 0; gg < 8; gg++) {
        float a = __shfl(att, (lane & 56) | gg);
        short8 v8 = *(const short8*)(vp + gg * 64);
        #pragma unroll
        for (int j = 0; j < 8; j++) o8[j] += a * bf2f((ushort)v8[j]);
    }
    short8 ov;
    #pragma unroll
    for (int j = 0; j < 8; j++) ov[j] = (short)f2bf(o8[j]);
    *(short8*)(hid + pos * 512 + lane * 8) = ov;
}

// ---------------- proj GEMM + bias + LN'd residual + new stats -------------
// tmp_new = hid @ woT^T + bo + LN_prev(tmp_old); stats of tmp_new -> ps/pss.
// BM=32, BN=128, grid (52,4), 256 thr (r8 core + r9 epilogue).
__global__ __launch_bounds__(256) void proj_fold(
    const ushort* __restrict__ A, const ushort* __restrict__ Bt,
    const float* __restrict__ bo_, const float* __restrict__ psin,
    const float* __restrict__ pssin, const float* __restrict__ g_in,
    const float* __restrict__ b_in, ushort* tmp,
    float* __restrict__ psout, float* __restrict__ pssout) {
    __shared__ alignas(16) ushort As[2][32 * 64];    // 2 x 4 KB
    __shared__ alignas(16) ushort Bs[2][128 * 64];   // 2 x 16 KB
    __shared__ float lps[2][32], lpss[2][32];
    __shared__ float smu[32], srs[32];
    const int tid = threadIdx.x;
    const int lane = tid & 63;
    const int wave = tid >> 6;            // 0..3
    const int m0 = blockIdx.x * 32;
    const int n0 = blockIdx.y * 128;
    const int wm = (wave >> 1) * 16;      // 0 | 16
    const int wn = (wave & 1) * 64;       // 0 | 64
    const int r = lane & 15;
    const int kq = (lane >> 4) * 8;
    const ushort* Ab = A  + (size_t)m0 * 512;
    const ushort* Bb = Bt + (size_t)n0 * 512;
    f32x4 acc[4] = {};

    auto stage = [&](int t, int b) {
        const ushort* At = Ab + t * 64;
        const ushort* Bt2 = Bb + t * 64;
        {                                            // A: 256 chunks
            int cb = wave * 64;
            int ch = cb + lane;
            int row = ch >> 3;
            int c8 = (ch & 7) ^ (row & 7);
            gload_lds16(At + (size_t)row * 512 + c8 * 8, (char*)As[b] + cb * 16);
        }
        #pragma unroll
        for (int i = 0; i < 4; i++) {                // B: 1024 chunks
            int cb = (i * 4 + wave) * 64;
            int ch = cb + lane;
            int row = ch >> 3;
            int c8 = (ch & 7) ^ (row & 7);
            gload_lds16(Bt2 + (size_t)row * 512 + c8 * 8, (char*)Bs[b] + cb * 16);
        }
    };

    stage(0, 0);
    if (tid < 32) {                        // prev-layer stats (overlaps stage)
        int row = m0 + tid;
        float s  = psin[row] + psin[1664 + row] + psin[3328 + row] + psin[4992 + row];
        float ss = pssin[row] + pssin[1664 + row] + pssin[3328 + row] + pssin[4992 + row];
        float mean = s * (1.f / 512.f);
        float var = ss * (1.f / 512.f) - mean * mean;
        smu[tid] = mean;
        srs[tid] = rsqrtf(var + 1e-5f);
    }
    __syncthreads();
    #pragma unroll
    for (int t = 0; t < 8; t++) {
        const int cur = t & 1;
        if (t < 7) stage(t + 1, cur ^ 1);
        #pragma unroll
        for (int kk = 0; kk < 64; kk += 32) {
            int arow = wm + r;
            int aoff = (arow * 128 + (kk + kq) * 2) ^ ((arow & 7) << 4);
            short8 af = *(const short8*)((const char*)As[cur] + aoff);
            #pragma unroll
            for (int n = 0; n < 4; n++) {
                int brow = wn + n * 16 + r;
                int boff = (brow * 128 + (kk + kq) * 2) ^ ((brow & 7) << 4);
                short8 bfr = *(const short8*)((const char*)Bs[cur] + boff);
                acc[n] = __builtin_amdgcn_mfma_f32_16x16x32_bf16(
                    af, bfr, acc[n], 0, 0, 0);
            }
        }
        __syncthreads();
    }

    // epilogue: v = acc + bo + LN_prev(tmp_old); write tmp; partial stats
    const int r4 = (lane >> 4) * 4;
    const int cc = lane & 15;
    float s_i[4] = {0.f, 0.f, 0.f, 0.f}, ss_i[4] = {0.f, 0.f, 0.f, 0.f};
    #pragma unroll
    for (int n = 0; n < 4; n++) {
        int col = n0 + wn + n * 16 + cc;
        float boc = bo_[col];
        float gc = g_in[col], bc = b_in[col];
        #pragma unroll
        for (int i = 0; i < 4; i++) {
            int lr = wm + r4 + i;
            int rg = m0 + lr;
            float resid = (bf2f(tmp[(size_t)rg * 512 + col]) - smu[lr])
                          * srs[lr] * gc + bc;
            float v = acc[n][i] + boc + resid;
            tmp[(size_t)rg * 512 + col] = f2bf(v);    // same elem: safe
            s_i[i] += v; ss_i[i] += v * v;
        }
    }
    #pragma unroll
    for (int i = 0; i < 4; i++) {
        #pragma unroll
        for (int o = 1; o < 16; o <<= 1) {
            s_i[i] += __shfl_xor(s_i[i], o);
            ss_i[i] += __shfl_xor(ss_i[i], o);
        }
    }
    if (cc == 0) {
        #pragma unroll
        for (int i = 0; i < 4; i++) {
            lps[wn >> 6][wm + r4 + i] = s_i[i];
            lpss[wn >> 6][wm + r4 + i] = ss_i[i];
        }
    }
    __syncthreads();
    if (tid < 32) {
        int row = m0 + tid;
        psout[blockIdx.y * 1664 + row]  = lps[0][tid] + lps[1][tid];
        pssout[blockIdx.y * 1664 + row] = lpss[0][tid] + lpss[1][tid];
    }
}

// ---------------- logits with final LN inline (r11 verbatim) ---------------
__global__ __launch_bounds__(256) void logits_ln(
    const ushort* __restrict__ tin, const float* __restrict__ psin,
    const float* __restrict__ pssin, const float* __restrict__ gv,
    const float* __restrict__ bv, const float* __restrict__ Wlm,
    const float* __restrict__ blm, float* __restrict__ lu) {
    __shared__ float wl[8 * 64 * 13];
    const int tid = threadIdx.x;
    for (int k = tid; k < 512; k += 256) {
        int dst = ((k & 7) * 64 + (k >> 3)) * 13;
        #pragma unroll
        for (int v = 0; v < 13; v++) wl[dst + v] = Wlm[k * 13 + v];
    }
    __syncthreads();
    const int lane = tid & 63;
    const int w = tid >> 6;
    const int c0 = lane * 8;
    float4 g0 = *(const float4*)(gv + c0), g1 = *(const float4*)(gv + c0 + 4);
    float4 b0 = *(const float4*)(bv + c0), b1 = *(const float4*)(bv + c0 + 4);
    float gg[8] = {g0.x, g0.y, g0.z, g0.w, g1.x, g1.y, g1.z, g1.w};
    float bb[8] = {b0.x, b0.y, b0.z, b0.w, b1.x, b1.y, b1.z, b1.w};
    float bl[13];
    #pragma unroll
    for (int v = 0; v < 13; v++) bl[v] = blm[v];
    for (int it = 0; it < 8; it++) {
        size_t row = (size_t)blockIdx.x * 32 + it * 4 + w;   // < 1664
        float s  = psin[row] + psin[1664 + row] + psin[3328 + row] + psin[4992 + row];
        float ss = pssin[row] + pssin[1664 + row] + pssin[3328 + row] + pssin[4992 + row];
        float mean = s * (1.f / 512.f);
        float rstd = rsqrtf(ss * (1.f / 512.f) - mean * mean + 1e-5f);
        short8 xv = *(const short8*)(tin + row * 512 + c0);
        float p[13];
        #pragma unroll
        for (int v = 0; v < 13; v++) p[v] = 0.f;
        #pragma unroll
        for (int j = 0; j < 8; j++) {
            float xf = (bf2f((ushort)xv[j]) - mean) * rstd * gg[j] + bb[j];
            const float* wr = wl + (j * 64 + lane) * 13;
            #pragma unroll
            for (int v = 0; v < 13; v++) p[v] += xf * wr[v];
        }
        #pragma unroll
        for (int v = 0; v < 13; v++) {
            #pragma unroll
            for (int o = 32; o > 0; o >>= 1) p[v] += __shfl_xor(p[v], o);
        }
        if (lane == 0) {
            #pragma unroll
            for (int v = 0; v < 13; v++) lu[row * 13 + v] = p[v] + bl[v];
        }
    }
}

// ---------------- scatter + loss (merged, proven) ---------------------------
__global__ __launch_bounds__(256) void scatter_loss(
    const float* __restrict__ lu, const int* __restrict__ tok,
    const int* __restrict__ label, float* __restrict__ out) {
    __shared__ float red[4];
    const int tid = threadIdx.x;
    if (blockIdx.x < 3328) {
        unsigned int i = blockIdx.x * 256 + tid;      // < 851968 exactly
        unsigned int bt = i / 13u;
        unsigned int vv = i - bt * 13u;
        int v = tok[bt];
        int t = (int)(bt & 127u);
        out[i] = lu[(size_t)((v << 7) + t) * 13 + vv];
    } else {
        float acc = 0.f;
        for (int b = tid; b < 512; b += 256) {
            int v = tok[b * 128 + 127];
            const float* lg = lu + (size_t)((v << 7) + 127) * 13;
            float mx = lg[0];
            #pragma unroll
            for (int vv = 1; vv < 13; vv++) mx = fmaxf(mx, lg[vv]);
            float den = 0.f;
            #pragma unroll
            for (int vv = 0; vv < 13; vv++) den += expf(lg[vv] - mx);
            int lab = label[b];
            acc += -(lg[lab] - mx - logf(den));
        }
        #pragma unroll
        for (int o = 32; o > 0; o >>= 1) acc += __shfl_xor(acc, o);
        if ((tid & 63) == 0) red[tid >> 6] = acc;
        __syncthreads();
        if (tid == 0)
            out[851968] = (red[0] + red[1] + red[2] + red[3]) * (1.f / 512.f);
    }
}

// ---------------------------------------------------------------------------
extern "C" void kernel_launch(void* const* d_in, const int* in_sizes, int n_in,
                              void* d_out, int out_size, void* d_ws, size_t ws_size,
                              hipStream_t stream) {
    const int*   tok   = (const int*)d_in[0];
    const int*   label = (const int*)d_in[1];
    const float* wte   = (const float*)d_in[2];
    const float* wpe   = (const float*)d_in[3];
    const float* Wq    = (const float*)d_in[4];
    const float* bq    = (const float*)d_in[5];
    const float* Wk    = (const float*)d_in[6];
    const float* bk    = (const float*)d_in[7];
    const float* Wv    = (const float*)d_in[8];
    const float* bv    = (const float*)d_in[9];
    const float* Wo    = (const float*)d_in[10];
    const float* bo    = (const float*)d_in[11];
    const float* ln_g  = (const float*)d_in[12];
    const float* ln_b  = (const float*)d_in[13];
    const float* Wlm   = (const float*)d_in[14];
    const float* blm   = (const float*)d_in[15];
    float* out = (float*)d_out;

    char* ws = (char*)d_ws;
    ushort* wqkvT = (ushort*)(ws);                 //  9,437,184
    ushort* woT   = (ushort*)(ws + 9437184);       //  3,145,728
    ushort* qkv_u = (ushort*)(ws + 12582912);      //  5,111,808
    ushort* hid_u = (ushort*)(ws + 17694720);      //  1,703,936
    ushort* tmp   = (ushort*)(ws + 19398656);      //  1,703,936
    float*  psA   = (float*) (ws + 21102592);
    float*  pssA  = (float*) (ws + 21129216);
    float*  psB   = (float*) (ws + 21155840);
    float*  pssB  = (float*) (ws + 21182464);
    float*  lu    = (float*) (ws + 21209088);
    float*  s_qkv = (float*) (ws + 21295616);
    float*  t_qkv = (float*) (ws + 21332480);
    float*  ones  = (float*) (ws + 21369344);
    float*  zeros = (float*) (ws + 21371392);

    prep_all<<<661, 256, 0, stream>>>(Wq, Wk, Wv, Wo, wte, wpe, ln_g, ln_b,
                                      wqkvT, woT, tmp, s_qkv, t_qkv,
                                      psA, pssA, ones, zeros);

    const float *psin = psA, *pssin = pssA;
    float *psout = psB, *pssout = pssB;
    for (int l = 0; l < 6; l++) {
        const float* g_in = (l == 0) ? ones  : ln_g + (l - 1) * 512;
        const float* b_in = (l == 0) ? zeros : ln_b + (l - 1) * 512;
        qkv_fold<<<dim3(26, 12), 256, 0, stream>>>(
            tmp, psin, pssin, wqkvT + (size_t)l * 786432,
            s_qkv + l * 1536, t_qkv + l * 1536,
            bq + l * 512, bk + l * 512, bv + l * 512, qkv_u);
        attn_kernel<<<416, 256, 0, stream>>>(qkv_u, hid_u);
        proj_fold<<<dim3(52, 4), 256, 0, stream>>>(
            hid_u, woT + (size_t)l * 262144, bo + l * 512,
            psin, pssin, g_in, b_in, tmp, psout, pssout);
        const float* p1 = psin;  psin = psout;  psout = (float*)p1;
        const float* p2 = pssin; pssin = pssout; pssout = (float*)p2;
    }

    logits_ln<<<52, 256, 0, stream>>>(tmp, psin, pssin,
                                      ln_g + 5 * 512, ln_b + 5 * 512, Wlm, blm, lu);
    scatter_loss<<<3329, 256, 0, stream>>>(lu, tok, label, out);
}